// Round 12
// baseline (140.933 us; speedup 1.0000x reference)
//
#include <hip/hip_runtime.h>
#include <hip/hip_bf16.h>

#define B 16
#define T 128
#define D 256
#define H 64
#define C1 64
#define C2 20
#define K2 4096   // H*C1
#define F2 1280   // H*C2
#define OUTW 32
#define ALPHA 0.2f

typedef __attribute__((ext_vector_type(8))) short short8;
typedef __attribute__((ext_vector_type(4))) float f32x4;

static __device__ __forceinline__ ushort f2bf(float f) {
    __hip_bfloat16 h = __float2bfloat16(f);
    return *reinterpret_cast<ushort*>(&h);
}
static __device__ __forceinline__ float bf2f(ushort u) {
    return __uint_as_float(((unsigned int)u) << 16);
}
// async global->LDS, 16B per lane; LDS dest is wave-uniform base + lane*16.
static __device__ __forceinline__ void gload16(const ushort* g, ushort* l) {
    __builtin_amdgcn_global_load_lds((const unsigned int*)g, (unsigned int*)l,
                                     16, 0, 0);
}

// ---------------------------------------------------------------------------
// Split-K MFMA GEMM for gemm2 (A in block-contiguous c1' layout
// [b][h][t][64]); PERM epilogue (fragment-native, coalesced uint2 bursts).
// M=2048 (tile = one b), N=1280, KSPLIT=8 (KDP=512 -> h = kp*8 + k0/64).
// ---------------------------------------------------------------------------
template<int NBLK, int MBLK, int KSPLIT>
__global__ __launch_bounds__(256) void gemm2_kernel(
    const ushort* __restrict__ Ag,   // c1' [B*H][128][64] bf16
    const ushort* __restrict__ Bg,   // w2t [1280][4096] bf16
    ushort* __restrict__ Cp)
{
    __shared__ ushort As[128 * 64];
    __shared__ ushort Bs[128 * 64];
    constexpr int KD = 4096;
    constexpr int NN = NBLK * 128;
    constexpr int MM = MBLK * 128;
    constexpr int NT = MBLK * NBLK;
    constexpr int TOTAL = NT * KSPLIT;
    constexpr int KDP = KD / KSPLIT;
    static_assert(TOTAL % 8 == 0, "swizzle needs multiple of 8 blocks");

    int tid = threadIdx.x;
    int bid = blockIdx.x;
    int wg = (bid & 7) * (TOTAL / 8) + (bid >> 3);
    int kp = wg / NT; int tile = wg - kp * NT;
    int bb = tile / NBLK, bn = (tile % NBLK) * 128;   // bb = batch index b

    int wave = tid >> 6, lane = tid & 63;
    int wm = (wave >> 1) * 64, wn = (wave & 1) * 64;
    int lr = lane & 15, lk = lane >> 4;
    int srow = lane >> 3, scol = (lane & 7) * 8;

    f32x4 acc[4][4];
    #pragma unroll
    for (int i = 0; i < 4; ++i)
        #pragma unroll
        for (int j = 0; j < 4; ++j) acc[i][j] = (f32x4){0.f, 0.f, 0.f, 0.f};

    const ushort* BpB = Bg + (size_t)bn * KD + kp * KDP;
    const ushort* ApB = Ag + (size_t)(bb * 64 + kp * 8) * 8192;  // h-base region

    for (int k0 = 0; k0 < KDP; k0 += 64) {
        int hh = k0 >> 6;                      // h offset within kp's 8 heads
        __syncthreads();
        #pragma unroll
        for (int e = 0; e < 4; ++e) {
            int c = e * 4 + wave;
            // A: c1'[(bb*64 + kp*8 + hh)][8c+srow][scol] — dense 1KB chunks
            gload16(ApB + (size_t)hh * 8192 + (8 * c + srow) * 64 + scol,
                    &As[c * 512]);
            gload16(BpB + (size_t)(8 * c + srow) * KD + k0 + scol, &Bs[c * 512]);
        }
        __syncthreads();
        #pragma unroll
        for (int ks = 0; ks < 2; ++ks) {
            short8 af[4], bfr[4];
            #pragma unroll
            for (int i = 0; i < 4; ++i)
                af[i] = *(const short8*)&As[(wm + i * 16 + lr) * 64 + ks * 32 + lk * 8];
            #pragma unroll
            for (int j = 0; j < 4; ++j)
                bfr[j] = *(const short8*)&Bs[(wn + j * 16 + lr) * 64 + ks * 32 + lk * 8];
            #pragma unroll
            for (int i = 0; i < 4; ++i)
                #pragma unroll
                for (int j = 0; j < 4; ++j)
                    acc[i][j] = __builtin_amdgcn_mfma_f32_16x16x32_bf16(
                        af[i], bfr[j], acc[i][j], 0, 0, 0);
        }
    }

    ushort* Cw = Cp + (size_t)kp * MM * NN + (size_t)tile * 16384
               + wave * 4096 + lane * 4;
    #pragma unroll
    for (int i = 0; i < 4; ++i)
        #pragma unroll
        for (int j = 0; j < 4; ++j) {
            union { ushort q[4]; uint2 v; } pk;
            #pragma unroll
            for (int r = 0; r < 4; ++r) pk.q[r] = f2bf(acc[i][j][r]);
            *(uint2*)&Cw[(i * 4 + j) * 256] = pk.v;
        }
}

// ---------------------------------------------------------------------------
// Split-K MFMA GEMM (row-major A/out) — sl path only.
// ---------------------------------------------------------------------------
template<int KD, int NBLK, int MBLK, int KSPLIT>
__global__ __launch_bounds__(256) void gemm_splitk_kernel(
    const ushort* __restrict__ Ag, const ushort* __restrict__ Bg,
    ushort* __restrict__ Cp)
{
    __shared__ ushort As[128 * 64];
    __shared__ ushort Bs[128 * 64];
    constexpr int NN = NBLK * 128;
    constexpr int MM = MBLK * 128;
    constexpr int NT = MBLK * NBLK;
    constexpr int TOTAL = NT * KSPLIT;
    constexpr int KDP = KD / KSPLIT;
    static_assert(TOTAL % 8 == 0, "swizzle needs multiple of 8 blocks");

    int tid = threadIdx.x;
    int bid = blockIdx.x;
    int wg = (bid & 7) * (TOTAL / 8) + (bid >> 3);
    int kp = wg / NT; int tile = wg - kp * NT;
    int bm = (tile / NBLK) * 128, bn = (tile % NBLK) * 128;

    int wave = tid >> 6, lane = tid & 63;
    int wm = (wave >> 1) * 64, wn = (wave & 1) * 64;
    int lr = lane & 15, lk = lane >> 4;
    int srow = lane >> 3, scol = (lane & 7) * 8;

    f32x4 acc[4][4];
    #pragma unroll
    for (int i = 0; i < 4; ++i)
        #pragma unroll
        for (int j = 0; j < 4; ++j) acc[i][j] = (f32x4){0.f, 0.f, 0.f, 0.f};

    const ushort* ApB = Ag + (size_t)bm * KD + kp * KDP;
    const ushort* BpB = Bg + (size_t)bn * KD + kp * KDP;

    for (int k0 = 0; k0 < KDP; k0 += 64) {
        __syncthreads();
        #pragma unroll
        for (int e = 0; e < 4; ++e) {
            int c = e * 4 + wave;
            gload16(ApB + (size_t)(8 * c + srow) * KD + k0 + scol, &As[c * 512]);
            gload16(BpB + (size_t)(8 * c + srow) * KD + k0 + scol, &Bs[c * 512]);
        }
        __syncthreads();
        #pragma unroll
        for (int ks = 0; ks < 2; ++ks) {
            short8 af[4], bfr[4];
            #pragma unroll
            for (int i = 0; i < 4; ++i)
                af[i] = *(const short8*)&As[(wm + i * 16 + lr) * 64 + ks * 32 + lk * 8];
            #pragma unroll
            for (int j = 0; j < 4; ++j)
                bfr[j] = *(const short8*)&Bs[(wn + j * 16 + lr) * 64 + ks * 32 + lk * 8];
            #pragma unroll
            for (int i = 0; i < 4; ++i)
                #pragma unroll
                for (int j = 0; j < 4; ++j)
                    acc[i][j] = __builtin_amdgcn_mfma_f32_16x16x32_bf16(
                        af[i], bfr[j], acc[i][j], 0, 0, 0);
        }
    }

    ushort* Cout = Cp + (size_t)kp * MM * NN;
    #pragma unroll
    for (int i = 0; i < 4; ++i) {
        #pragma unroll
        for (int j = 0; j < 4; ++j) {
            int col = bn + wn + j * 16 + lr;
            #pragma unroll
            for (int r = 0; r < 4; ++r) {
                int row = bm + wm + i * 16 + lk * 4 + r;
                Cout[(size_t)row * NN + col] = f2bf(acc[i][j][r]);
            }
        }
    }
}

// ---------------------------------------------------------------------------
// reduce P bf16 split-K partials + bias -> fp32 out (sl path).
// ---------------------------------------------------------------------------
template<int P, int NN>
__global__ __launch_bounds__(256) void reduce_bias_kernel(
    const ushort* __restrict__ parts, const float* __restrict__ bias,
    float* __restrict__ out, int MN)
{
    size_t off = ((size_t)blockIdx.x * 256 + threadIdx.x) * 4;
    float s0 = 0.f, s1 = 0.f, s2 = 0.f, s3 = 0.f;
    #pragma unroll
    for (int p = 0; p < P; ++p) {
        uint2 v = *(const uint2*)&parts[(size_t)p * MN + off];
        s0 += bf2f((ushort)(v.x & 0xffff));
        s1 += bf2f((ushort)(v.x >> 16));
        s2 += bf2f((ushort)(v.y & 0xffff));
        s3 += bf2f((ushort)(v.y >> 16));
    }
    float4 bv = *(const float4*)&bias[(int)(off % NN)];
    float4 o; o.x = s0 + bv.x; o.y = s1 + bv.y; o.z = s2 + bv.z; o.w = s3 + bv.w;
    *(float4*)&out[off] = o;
}

// ---------------------------------------------------------------------------
// FUSED kernel 1: Wh1 MFMA -> scores -> P~ -> PV MFMA -> c1' block-contiguous
// [b][h][t][64] (each block owns a private 16KB region: no cross-XCD line
// sharing -> no write amplification).
// ---------------------------------------------------------------------------
#define AS_(r,c)  u.stag[(r) * 72 + (c)]
#define BS_(r,c)  u.stag[9216 + (r) * 72 + (c)]
#define PB_(r,c)  u.Pb[(r) * 136 + (c)]
#define WHT_(r,c) whT[(r) * 136 + (c)]

__global__ __launch_bounds__(256) void fused1_kernel(
    const ushort* __restrict__ xbf,   // [B*T][256] bf16
    const ushort* __restrict__ w1t,   // [H*64][256] bf16
    const float* __restrict__ b1,     // [4096] ([h][c] flat)
    const float* __restrict__ a1s, const float* __restrict__ a1d,
    const float* __restrict__ a1b,
    ushort* __restrict__ c1)          // c1' [B*H][128][64]
{
    int blk = blockIdx.x; int b = blk >> 6, h = blk & 63;
    __shared__ union {
        ushort stag[128 * 72 + 64 * 72];
        ushort Pb[128 * 136];
    } u;
    __shared__ ushort whT[64 * 136];
    __shared__ float ss[128], ddv[128], sinv[128];

    int tid = threadIdx.x;
    int wave = tid >> 6, lane = tid & 63;
    int wm = (wave >> 1) * 64, wn = (wave & 1) * 32;
    int lr = lane & 15, lk = lane >> 4;
    int sr = tid >> 3, sc = (tid & 7) * 8;

    f32x4 acc[4][2];
    #pragma unroll
    for (int i = 0; i < 4; ++i)
        #pragma unroll
        for (int j = 0; j < 2; ++j) acc[i][j] = (f32x4){0.f, 0.f, 0.f, 0.f};

    const ushort* Ap = xbf + (size_t)(b * T + sr) * D + sc;
    const ushort* Bp = w1t + (size_t)(h * 64 + sr) * D + sc;

    uint4 ra[4], rb[2];
    #pragma unroll
    for (int e = 0; e < 4; ++e) ra[e] = *(const uint4*)(Ap + (size_t)e * 32 * D);
    #pragma unroll
    for (int e = 0; e < 2; ++e) rb[e] = *(const uint4*)(Bp + (size_t)e * 32 * D);

    for (int k0 = 0; k0 < D; k0 += 64) {
        __syncthreads();
        #pragma unroll
        for (int e = 0; e < 4; ++e) *(uint4*)&AS_(sr + e * 32, sc) = ra[e];
        if (sr < 32) {
            #pragma unroll
            for (int e = 0; e < 2; ++e) *(uint4*)&BS_(sr + e * 32, sc) = rb[e];
        }
        __syncthreads();
        if (k0 + 64 < D) {
            #pragma unroll
            for (int e = 0; e < 4; ++e)
                ra[e] = *(const uint4*)(Ap + (size_t)e * 32 * D + k0 + 64);
            #pragma unroll
            for (int e = 0; e < 2; ++e)
                rb[e] = *(const uint4*)(Bp + (size_t)e * 32 * D + k0 + 64);
        }
        #pragma unroll
        for (int ks = 0; ks < 2; ++ks) {
            short8 af[4], bfr[2];
            #pragma unroll
            for (int i = 0; i < 4; ++i)
                af[i] = *(const short8*)&AS_(wm + i * 16 + lr, ks * 32 + lk * 8);
            #pragma unroll
            for (int j = 0; j < 2; ++j)
                bfr[j] = *(const short8*)&BS_(wn + j * 16 + lr, ks * 32 + lk * 8);
            #pragma unroll
            for (int i = 0; i < 4; ++i)
                #pragma unroll
                for (int j = 0; j < 2; ++j)
                    acc[i][j] = __builtin_amdgcn_mfma_f32_16x16x32_bf16(
                        af[i], bfr[j], acc[i][j], 0, 0, 0);
        }
    }

    #pragma unroll
    for (int j = 0; j < 2; ++j) {
        int col = wn + j * 16 + lr;
        float bv = b1[h * C1 + col];
        #pragma unroll
        for (int i = 0; i < 4; ++i) {
            int t0 = wm + i * 16 + lk * 4;
            union { ushort q[4]; uint2 v; } pk;
            #pragma unroll
            for (int r = 0; r < 4; ++r) pk.q[r] = f2bf(acc[i][j][r] + bv);
            *(uint2*)&WHT_(col, t0) = pk.v;
        }
    }
    __syncthreads();

    {
        int t = tid & 127;
        bool isS = tid < 128;
        const float* av = (isS ? a1s : a1d) + h * C1;
        float s = isS ? a1b[h] : 0.f;
        #pragma unroll 8
        for (int c = 0; c < 64; ++c) s = fmaf(bf2f(WHT_(c, t)), av[c], s);
        if (isS) ss[t] = s; else ddv[t] = s;
    }
    __syncthreads();

    {
        float dm = fmaxf(ddv[lane], ddv[lane + 64]);
        #pragma unroll
        for (int msk = 1; msk < 64; msk <<= 1) dm = fmaxf(dm, __shfl_xor(dm, msk));
        int i = tid >> 1, j0 = (tid & 1) * 64;
        float si = ss[i];
        float mx = si + dm; mx = mx >= 0.f ? mx : ALPHA * mx;
        float lsum = 0.f;
        #pragma unroll
        for (int g = 0; g < 8; ++g) {
            union { ushort q[8]; uint4 v; } pk;
            #pragma unroll
            for (int e = 0; e < 8; ++e) {
                float ee = si + ddv[j0 + g * 8 + e];
                ee = ee >= 0.f ? ee : ALPHA * ee;
                float pp = __expf(ee - mx);
                lsum += pp;
                pk.q[e] = f2bf(pp);
            }
            *(uint4*)&PB_(i, j0 + g * 8) = pk.v;
        }
        lsum += __shfl_xor(lsum, 1);
        if (!(tid & 1)) sinv[i] = 1.0f / lsum;
    }
    __syncthreads();

    f32x4 acc2[4][2];
    #pragma unroll
    for (int i = 0; i < 4; ++i)
        #pragma unroll
        for (int j = 0; j < 2; ++j) acc2[i][j] = (f32x4){0.f, 0.f, 0.f, 0.f};

    #pragma unroll
    for (int ks = 0; ks < 4; ++ks) {
        short8 af[4], bfr[2];
        #pragma unroll
        for (int i = 0; i < 4; ++i)
            af[i] = *(const short8*)&PB_(wm + i * 16 + lr, ks * 32 + lk * 8);
        #pragma unroll
        for (int j = 0; j < 2; ++j)
            bfr[j] = *(const short8*)&WHT_(wn + j * 16 + lr, ks * 32 + lk * 8);
        #pragma unroll
        for (int i = 0; i < 4; ++i)
            #pragma unroll
            for (int j = 0; j < 2; ++j)
                acc2[i][j] = __builtin_amdgcn_mfma_f32_16x16x32_bf16(
                    af[i], bfr[j], acc2[i][j], 0, 0, 0);
    }

    // ---- epilogue: restage in LDS (reuse Pb), then sequential uint4 out ----
    __syncthreads();                       // all PV ds_reads complete
    ushort* CT = u.Pb;                     // [128][72] (stride 72 => 16B align)
    #pragma unroll
    for (int i = 0; i < 4; ++i) {
        #pragma unroll
        for (int r = 0; r < 4; ++r) {
            int row = wm + i * 16 + lk * 4 + r;
            float sv = sinv[row];
            #pragma unroll
            for (int j = 0; j < 2; ++j) {
                int col = wn + j * 16 + lr;
                float v = acc2[i][j][r] * sv;
                v = v > 0.f ? v : 0.f;
                v = 1.0f / (1.0f + __expf(-v));
                CT[row * 72 + col] = f2bf(v);
            }
        }
    }
    __syncthreads();
    // block-private 16KB region: fully sequential 4KB bursts per pass
    ushort* c1blk = c1 + (size_t)blk * (128 * 64);
    #pragma unroll
    for (int e = 0; e < 4; ++e) {
        int idx = e * 256 + tid;           // 0..1023: row = idx>>3, q = idx&7
        int row = idx >> 3, q = idx & 7;
        uint4 v = *(const uint4*)&CT[row * 72 + q * 8];
        *(uint4*)&c1blk[row * 64 + q * 8] = v;
    }
}

// ---------------------------------------------------------------------------
// FUSED kernel 2: split-K reduce (+bias) from PERMUTED partials -> scores ->
// P~ -> PV MFMA -> coalesced c2 write via LDS restage.
// ---------------------------------------------------------------------------
#define PB2_(r,c)  Pb2[(r) * 136 + (c)]
#define WHT2_(r,c) whT2[(r) * 136 + (c)]

__global__ __launch_bounds__(256) void fused2_kernel(
    const ushort* __restrict__ wh2pb,  // [8] x permuted [2048][1280] bf16
    const float* __restrict__ b2,      // [1280] ([h][c] flat)
    const float* __restrict__ a2s, const float* __restrict__ a2d,
    const float* __restrict__ a2b,
    ushort* __restrict__ c2)
{
    int blk = blockIdx.x; int b = blk >> 6, h = blk & 63;
    __shared__ ushort Pb2[128 * 136];
    __shared__ ushort whT2[32 * 136];
    __shared__ float ss[128], ddv[128], sinv[128];

    int tid = threadIdx.x;
    int wave = tid >> 6, lane = tid & 63;
    int lr = lane & 15, lk = lane >> 4;
    const size_t MNfull = (size_t)2048 * F2;

    // ---- load + split-K reduce (permuted layout) + transpose ----
    for (int e = 0; e < 10; ++e) {
        int idx = e * 256 + tid;               // 0..2559
        int t = idx / 20, c = idx - t * 20;
        int col = h * C2 + c;
        int tn = col >> 7, cl = col & 127;
        int wv = ((t >> 6) << 1) | (cl >> 6);
        int fi = (t >> 4) & 3, fk = (t >> 2) & 3, fr = t & 3;
        int fj = (cl >> 4) & 3, fl = cl & 15;
        size_t fa = (size_t)(b * 10 + tn) * 16384 + wv * 4096
                  + (fi * 4 + fj) * 256 + (fk * 16 + fl) * 4 + fr;
        float s = b2[col];
        #pragma unroll
        for (int p = 0; p < 8; ++p) s += bf2f(wh2pb[p * MNfull + fa]);
        WHT2_(c, t) = f2bf(s);
    }
    {   // zero-pad rows 20..31
        int idx = tid;
        for (int e = 0; e < 6; ++e, idx += 256) {
            int c = 20 + (idx >> 7), t = idx & 127;
            WHT2_(c, t) = 0;
        }
    }
    __syncthreads();

    // ---- scores ----
    {
        int t = tid & 127;
        bool isS = tid < 128;
        const float* av = (isS ? a2s : a2d) + h * C2;
        float s = isS ? a2b[h] : 0.f;
        #pragma unroll
        for (int c = 0; c < 20; ++c) s = fmaf(bf2f(WHT2_(c, t)), av[c], s);
        if (isS) ss[t] = s; else ddv[t] = s;
    }
    __syncthreads();

    // ---- P~ + row sums ----
    {
        float dm = fmaxf(ddv[lane], ddv[lane + 64]);
        #pragma unroll
        for (int msk = 1; msk < 64; msk <<= 1) dm = fmaxf(dm, __shfl_xor(dm, msk));
        int i = tid >> 1, j0 = (tid & 1) * 64;
        float si = ss[i];
        float mx = si + dm; mx = mx >= 0.f ? mx : ALPHA * mx;
        float lsum = 0.f;
        #pragma unroll
        for (int g = 0; g < 8; ++g) {
            union { ushort q[8]; uint4 v; } pk;
            #pragma unroll
            for (int e = 0; e < 8; ++e) {
                float ee = si + ddv[j0 + g * 8 + e];
                ee = ee >= 0.f ? ee : ALPHA * ee;
                float pp = __expf(ee - mx);
                lsum += pp;
                pk.q[e] = f2bf(pp);
            }
            *(uint4*)&PB2_(i, j0 + g * 8) = pk.v;
        }
        lsum += __shfl_xor(lsum, 1);
        if (!(tid & 1)) sinv[i] = 1.0f / lsum;
    }
    __syncthreads();

    // ---- PV: out[128][32] = P~ @ whT2^T; wave owns 32 rows ----
    int wm2 = wave * 32;
    f32x4 acc2[2][2];
    #pragma unroll
    for (int i = 0; i < 2; ++i)
        #pragma unroll
        for (int j = 0; j < 2; ++j) acc2[i][j] = (f32x4){0.f, 0.f, 0.f, 0.f};

    #pragma unroll
    for (int ks = 0; ks < 4; ++ks) {
        short8 af[2], bfr[2];
        #pragma unroll
        for (int i = 0; i < 2; ++i)
            af[i] = *(const short8*)&PB2_(wm2 + i * 16 + lr, ks * 32 + lk * 8);
        #pragma unroll
        for (int j = 0; j < 2; ++j)
            bfr[j] = *(const short8*)&WHT2_(j * 16 + lr, ks * 32 + lk * 8);
        #pragma unroll
        for (int i = 0; i < 2; ++i)
            #pragma unroll
            for (int j = 0; j < 2; ++j)
                acc2[i][j] = __builtin_amdgcn_mfma_f32_16x16x32_bf16(
                    af[i], bfr[j], acc2[i][j], 0, 0, 0);
    }

    // ---- coalesced epilogue via LDS restage (reuse Pb2) ----
    __syncthreads();
    ushort* CT2 = Pb2;                     // [128][24]
    #pragma unroll
    for (int i = 0; i < 2; ++i) {
        #pragma unroll
        for (int r = 0; r < 4; ++r) {
            int row = wm2 + i * 16 + lk * 4 + r;
            float sv = sinv[row];
            #pragma unroll
            for (int j = 0; j < 2; ++j) {
                int col = j * 16 + lr;
                if (col < C2) {
                    float v = acc2[i][j][r] * sv;
                    v = v > 0.f ? v : 0.f;
                    v = 1.0f / (1.0f + __expf(-v));
                    CT2[row * 24 + col] = f2bf(v);
                }
            }
        }
    }
    __syncthreads();
    for (int e = 0; e < 3; ++e) {
        int idx = e * 256 + tid;           // 0..639: row = idx/5, q = idx%5
        if (idx < 640) {
            int row = idx / 5, q = idx - row * 5;
            uint2 v = *(const uint2*)&CT2[row * 24 + q * 4];
            *(uint2*)&c2[((size_t)(b * T + row)) * F2 + h * C2 + q * 4] = v;
        }
    }
}

// ---------------------------------------------------------------------------
// Prep kernels
// ---------------------------------------------------------------------------
__global__ __launch_bounds__(256) void xbf_kernel(
    const float* __restrict__ x, ushort* __restrict__ xbf)
{
    int i = blockIdx.x * 256 + threadIdx.x;
    float4 v = *(const float4*)&x[(size_t)i * 4];
    union { ushort u[4]; uint2 p; } o;
    o.u[0] = f2bf(v.x); o.u[1] = f2bf(v.y);
    o.u[2] = f2bf(v.z); o.u[3] = f2bf(v.w);
    *(uint2*)&xbf[(size_t)i * 4] = o.p;
}

__global__ __launch_bounds__(256) void w1t_kernel(
    const float* __restrict__ W1, ushort* __restrict__ w1t)
{
    int blk = blockIdx.x; int h = blk >> 2, d0 = (blk & 3) * 64;
    __shared__ float lw[64][65];
    int tid = threadIdx.x;
    for (int e = 0; e < 16; ++e) {
        int idx = e * 256 + tid; int dr = idx >> 6, c = idx & 63;
        lw[dr][c] = W1[((size_t)h * D + d0 + dr) * C1 + c];
    }
    __syncthreads();
    for (int e = 0; e < 16; ++e) {
        int idx = e * 256 + tid; int c = idx >> 6, dr = idx & 63;
        w1t[((size_t)(h * 64 + c)) * D + d0 + dr] = f2bf(lw[dr][c]);
    }
}

__global__ __launch_bounds__(256) void w2t_kernel(
    const float* __restrict__ W2, ushort* __restrict__ w2t)
{
    int blk = blockIdx.x; int h = blk >> 5, kb = blk & 31; int k0 = kb * 128;
    __shared__ float lw[128][21];
    int tid = threadIdx.x;
    const float* src = W2 + ((size_t)h * K2 + k0) * C2;
    for (int e = 0; e < 10; ++e) {
        int idx = e * 256 + tid; int k = idx / 20, c = idx - k * 20;
        lw[k][c] = src[idx];
    }
    __syncthreads();
    for (int e = 0; e < 10; ++e) {
        int idx = e * 256 + tid; int c = idx >> 7, k = idx & 127;
        w2t[((size_t)(h * 20 + c)) * K2 + k0 + k] = f2bf(lw[k][c]);
    }
}

__global__ __launch_bounds__(256) void slwt_kernel(
    const float* __restrict__ slw, ushort* __restrict__ slwt)
{
    int blk = blockIdx.x; int kb = blk >> 2, d0 = (blk & 3) * 64; int k0 = kb * 64;
    __shared__ float lw[64][65];
    int tid = threadIdx.x;
    for (int e = 0; e < 16; ++e) {
        int idx = e * 256 + tid; int kr = idx >> 6, dc = idx & 63;
        lw[kr][dc] = slw[((size_t)(k0 + kr)) * D + d0 + dc];
    }
    __syncthreads();
    for (int e = 0; e < 16; ++e) {
        int idx = e * 256 + tid; int dr = idx >> 6, kc = idx & 63;
        slwt[((size_t)(d0 + dr)) * F2 + k0 + kc] = f2bf(lw[kc][dr]);
    }
}

// ---------------------------------------------------------------------------
// GAR: res[b,o,d] = sum_t c3[b,t,d]*gar_w[t,o] + gar_b[o]
// ---------------------------------------------------------------------------
__global__ __launch_bounds__(256) void gar_kernel(
    const float* __restrict__ c3, const float* __restrict__ garw,
    const float* __restrict__ garb, float* __restrict__ out)
{
    int blk = blockIdx.x; int b = blk >> 5, o = blk & 31;
    int dcol = threadIdx.x;
    float acc = garb[o];
    const float* cp = c3 + (size_t)b * T * D + dcol;
    for (int t = 0; t < T; ++t)
        acc = fmaf(cp[(size_t)t * D], garw[t * OUTW + o], acc);
    out[((size_t)b * OUTW + o) * D + dcol] = acc;
}

// ---------------------------------------------------------------------------
extern "C" void kernel_launch(void* const* d_in, const int* in_sizes, int n_in,
                              void* d_out, int out_size, void* d_ws, size_t ws_size,
                              hipStream_t stream) {
    const float* x    = (const float*)d_in[0];
    const float* W1   = (const float*)d_in[1];
    const float* b1   = (const float*)d_in[2];
    const float* a1s  = (const float*)d_in[3];
    const float* a1d  = (const float*)d_in[4];
    const float* a1b  = (const float*)d_in[5];
    const float* W2   = (const float*)d_in[6];
    const float* b2   = (const float*)d_in[7];
    const float* a2s  = (const float*)d_in[8];
    const float* a2d  = (const float*)d_in[9];
    const float* a2b  = (const float*)d_in[10];
    const float* slw  = (const float*)d_in[11];
    const float* slb  = (const float*)d_in[12];
    const float* garw = (const float*)d_in[13];
    const float* garb = (const float*)d_in[14];

    char* p = (char*)d_ws;
    float*  c3    = (float*)p;   p += (size_t)2048 * 256  * 4;     //  2.1 MB
    ushort* xbf   = (ushort*)p;  p += (size_t)2048 * 256  * 2;     //  1.0 MB
    ushort* w1t   = (ushort*)p;  p += (size_t)4096 * 256  * 2;     //  2.1 MB
    ushort* c1bf  = (ushort*)p;  p += (size_t)2048 * 4096 * 2;     // 16.8 MB
    ushort* w2t   = (ushort*)p;  p += (size_t)1280 * 4096 * 2;     // 10.5 MB
    ushort* c2bf  = (ushort*)p;  p += (size_t)2048 * 1280 * 2;     //  5.2 MB
    ushort* slwt  = (ushort*)p;  p += (size_t)256  * 1280 * 2;     //  0.7 MB
    ushort* wh2pb = (ushort*)p;  p += (size_t)8 * 2048 * 1280 * 2; // 42 MB
    ushort* c3pb  = (ushort*)c1bf;   // aliases c1bf (dead after gemm2 reads it)

    xbf_kernel <<<512,  256, 0, stream>>>(x, xbf);
    w1t_kernel <<<256,  256, 0, stream>>>(W1, w1t);
    w2t_kernel <<<2048, 256, 0, stream>>>(W2, w2t);
    slwt_kernel<<<80,   256, 0, stream>>>(slw, slwt);

    fused1_kernel<<<B * H, 256, 0, stream>>>(xbf, w1t, b1, a1s, a1d, a1b, c1bf);

    gemm2_kernel<10, 16, 8><<<1280, 256, 0, stream>>>(c1bf, w2t, wh2pb);
    fused2_kernel<<<B * H, 256, 0, stream>>>(wh2pb, b2, a2s, a2d, a2b, c2bf);

    gemm_splitk_kernel<1280, 2, 16, 4><<<128, 256, 0, stream>>>(c2bf, slwt,
                                                                c3pb);
    reduce_bias_kernel<4, 256><<<512, 256, 0, stream>>>(c3pb, slb, c3, 2048 * 256);

    gar_kernel<<<B * OUTW, 256, 0, stream>>>(c3, garw, garb, (float*)d_out);
}

// Round 14
// 133.020 us; speedup vs baseline: 1.0595x; 1.0595x over previous
//
#include <hip/hip_runtime.h>
#include <hip/hip_bf16.h>

#define B 16
#define T 128
#define D 256
#define H 64
#define C1 64
#define C2 20
#define K2 4096   // H*C1
#define F2 1280   // H*C2
#define OUTW 32
#define ALPHA 0.2f

typedef __attribute__((ext_vector_type(8))) short short8;
typedef __attribute__((ext_vector_type(4))) float f32x4;

static __device__ __forceinline__ ushort f2bf(float f) {
    __hip_bfloat16 h = __float2bfloat16(f);
    return *reinterpret_cast<ushort*>(&h);
}
static __device__ __forceinline__ float bf2f(ushort u) {
    return __uint_as_float(((unsigned int)u) << 16);
}
// async global->LDS, 16B per lane; LDS dest is wave-uniform base + lane*16.
static __device__ __forceinline__ void gload16(const ushort* g, ushort* l) {
    __builtin_amdgcn_global_load_lds((const unsigned int*)g, (unsigned int*)l,
                                     16, 0, 0);
}

// ---------------------------------------------------------------------------
// Split-K MFMA GEMM (verified round 8) + PERM epilogue:
// PERM=1 -> fragment-native layout, fully coalesced uint2 stores:
//   addr = kp*MM*NN + tile*16384 + wave*4096 + (i*4+j)*256 + lane*4 + r
// PERM=0 -> row-major scalar stores (sl GEMM).
// ---------------------------------------------------------------------------
template<int KD, int NBLK, int MBLK, int KSPLIT, int PERM>
__global__ __launch_bounds__(256) void gemm_splitk_kernel(
    const ushort* __restrict__ Ag, const ushort* __restrict__ Bg,
    ushort* __restrict__ Cp)
{
    __shared__ ushort As[128 * 64];
    __shared__ ushort Bs[128 * 64];
    constexpr int NN = NBLK * 128;
    constexpr int MM = MBLK * 128;
    constexpr int NT = MBLK * NBLK;
    constexpr int TOTAL = NT * KSPLIT;
    constexpr int KDP = KD / KSPLIT;
    static_assert(TOTAL % 8 == 0, "swizzle needs multiple of 8 blocks");

    int tid = threadIdx.x;
    int bid = blockIdx.x;
    int wg = (bid & 7) * (TOTAL / 8) + (bid >> 3);
    int kp = wg / NT; int tile = wg - kp * NT;
    int bm = (tile / NBLK) * 128, bn = (tile % NBLK) * 128;

    int wave = tid >> 6, lane = tid & 63;
    int wm = (wave >> 1) * 64, wn = (wave & 1) * 64;
    int lr = lane & 15, lk = lane >> 4;
    int srow = lane >> 3, scol = (lane & 7) * 8;

    f32x4 acc[4][4];
    #pragma unroll
    for (int i = 0; i < 4; ++i)
        #pragma unroll
        for (int j = 0; j < 4; ++j) acc[i][j] = (f32x4){0.f, 0.f, 0.f, 0.f};

    const ushort* ApB = Ag + (size_t)bm * KD + kp * KDP;
    const ushort* BpB = Bg + (size_t)bn * KD + kp * KDP;

    for (int k0 = 0; k0 < KDP; k0 += 64) {
        __syncthreads();
        #pragma unroll
        for (int e = 0; e < 4; ++e) {
            int c = e * 4 + wave;
            gload16(ApB + (size_t)(8 * c + srow) * KD + k0 + scol, &As[c * 512]);
            gload16(BpB + (size_t)(8 * c + srow) * KD + k0 + scol, &Bs[c * 512]);
        }
        __syncthreads();
        #pragma unroll
        for (int ks = 0; ks < 2; ++ks) {
            short8 af[4], bfr[4];
            #pragma unroll
            for (int i = 0; i < 4; ++i)
                af[i] = *(const short8*)&As[(wm + i * 16 + lr) * 64 + ks * 32 + lk * 8];
            #pragma unroll
            for (int j = 0; j < 4; ++j)
                bfr[j] = *(const short8*)&Bs[(wn + j * 16 + lr) * 64 + ks * 32 + lk * 8];
            #pragma unroll
            for (int i = 0; i < 4; ++i)
                #pragma unroll
                for (int j = 0; j < 4; ++j)
                    acc[i][j] = __builtin_amdgcn_mfma_f32_16x16x32_bf16(
                        af[i], bfr[j], acc[i][j], 0, 0, 0);
        }
    }

    if constexpr (PERM) {
        ushort* Cw = Cp + (size_t)kp * MM * NN + (size_t)tile * 16384
                   + wave * 4096 + lane * 4;
        #pragma unroll
        for (int i = 0; i < 4; ++i)
            #pragma unroll
            for (int j = 0; j < 4; ++j) {
                union { ushort q[4]; uint2 v; } pk;
                #pragma unroll
                for (int r = 0; r < 4; ++r) pk.q[r] = f2bf(acc[i][j][r]);
                *(uint2*)&Cw[(i * 4 + j) * 256] = pk.v;
            }
    } else {
        ushort* Cout = Cp + (size_t)kp * MM * NN;
        #pragma unroll
        for (int i = 0; i < 4; ++i) {
            #pragma unroll
            for (int j = 0; j < 4; ++j) {
                int col = bn + wn + j * 16 + lr;
                #pragma unroll
                for (int r = 0; r < 4; ++r) {
                    int row = bm + wm + i * 16 + lk * 4 + r;
                    Cout[(size_t)row * NN + col] = f2bf(acc[i][j][r]);
                }
            }
        }
    }
}

// ---------------------------------------------------------------------------
// reduce P bf16 split-K partials + bias -> fp32 out (sl path, PERM=0 layout).
// ---------------------------------------------------------------------------
template<int P, int NN>
__global__ __launch_bounds__(256) void reduce_bias_kernel(
    const ushort* __restrict__ parts, const float* __restrict__ bias,
    float* __restrict__ out, int MN)
{
    size_t off = ((size_t)blockIdx.x * 256 + threadIdx.x) * 4;
    float s0 = 0.f, s1 = 0.f, s2 = 0.f, s3 = 0.f;
    #pragma unroll
    for (int p = 0; p < P; ++p) {
        uint2 v = *(const uint2*)&parts[(size_t)p * MN + off];
        s0 += bf2f((ushort)(v.x & 0xffff));
        s1 += bf2f((ushort)(v.x >> 16));
        s2 += bf2f((ushort)(v.y & 0xffff));
        s3 += bf2f((ushort)(v.y >> 16));
    }
    float4 bv = *(const float4*)&bias[(int)(off % NN)];
    float4 o; o.x = s0 + bv.x; o.y = s1 + bv.y; o.z = s2 + bv.z; o.w = s3 + bv.w;
    *(float4*)&out[off] = o;
}

// ---------------------------------------------------------------------------
// FUSED kernel 1: Wh1 MFMA -> scores -> P~ -> PV MFMA -> c1 (row-major) via
// LDS restage. ss/ddv live in Pb's dead per-row pad (cols 128..135, 16B/row):
// P~ writes cols<128 only, PV reads cols<128 only, and ss/ddv are dead before
// the CT restage reuses low rows. sinv stays separate (epilogue reads it
// while CT writes could clobber low-row pads). LDS 53760 -> 52736 B.
// whT stride 136: REQUIRED >=128 (t-index), mult of 8 (16B align), and
// 68 dwords % 32 == 4 => bank-conflict-free b128 reads. DO NOT SHRINK.
// ---------------------------------------------------------------------------
#define AS_(r,c)  u.stag[(r) * 72 + (c)]
#define BS_(r,c)  u.stag[9216 + (r) * 72 + (c)]
#define PB_(r,c)  u.Pb[(r) * 136 + (c)]
#define WHT_(r,c) whT[(r) * 136 + (c)]
#define SS_(t)    (*(float*)&u.Pb[(t) * 136 + 128])
#define DDV_(t)   (*(float*)&u.Pb[(t) * 136 + 130])

__global__ __launch_bounds__(256) void fused1_kernel(
    const ushort* __restrict__ xbf,   // [B*T][256] bf16
    const ushort* __restrict__ w1t,   // [H*64][256] bf16
    const float* __restrict__ b1,     // [4096] ([h][c] flat)
    const float* __restrict__ a1s, const float* __restrict__ a1d,
    const float* __restrict__ a1b,
    ushort* __restrict__ c1)          // [B*T][4096] row-major
{
    int blk = blockIdx.x; int b = blk >> 6, h = blk & 63;
    __shared__ union {
        ushort stag[128 * 72 + 64 * 72];
        ushort Pb[128 * 136];
    } u;
    __shared__ ushort whT[64 * 136];
    __shared__ float sinv[128];

    int tid = threadIdx.x;
    int wave = tid >> 6, lane = tid & 63;
    int wm = (wave >> 1) * 64, wn = (wave & 1) * 32;
    int lr = lane & 15, lk = lane >> 4;
    int sr = tid >> 3, sc = (tid & 7) * 8;

    f32x4 acc[4][2];
    #pragma unroll
    for (int i = 0; i < 4; ++i)
        #pragma unroll
        for (int j = 0; j < 2; ++j) acc[i][j] = (f32x4){0.f, 0.f, 0.f, 0.f};

    const ushort* Ap = xbf + (size_t)(b * T + sr) * D + sc;
    const ushort* Bp = w1t + (size_t)(h * 64 + sr) * D + sc;

    uint4 ra[4], rb[2];
    #pragma unroll
    for (int e = 0; e < 4; ++e) ra[e] = *(const uint4*)(Ap + (size_t)e * 32 * D);
    #pragma unroll
    for (int e = 0; e < 2; ++e) rb[e] = *(const uint4*)(Bp + (size_t)e * 32 * D);

    for (int k0 = 0; k0 < D; k0 += 64) {
        __syncthreads();
        #pragma unroll
        for (int e = 0; e < 4; ++e) *(uint4*)&AS_(sr + e * 32, sc) = ra[e];
        if (sr < 32) {
            #pragma unroll
            for (int e = 0; e < 2; ++e) *(uint4*)&BS_(sr + e * 32, sc) = rb[e];
        }
        __syncthreads();
        if (k0 + 64 < D) {
            #pragma unroll
            for (int e = 0; e < 4; ++e)
                ra[e] = *(const uint4*)(Ap + (size_t)e * 32 * D + k0 + 64);
            #pragma unroll
            for (int e = 0; e < 2; ++e)
                rb[e] = *(const uint4*)(Bp + (size_t)e * 32 * D + k0 + 64);
        }
        #pragma unroll
        for (int ks = 0; ks < 2; ++ks) {
            short8 af[4], bfr[2];
            #pragma unroll
            for (int i = 0; i < 4; ++i)
                af[i] = *(const short8*)&AS_(wm + i * 16 + lr, ks * 32 + lk * 8);
            #pragma unroll
            for (int j = 0; j < 2; ++j)
                bfr[j] = *(const short8*)&BS_(wn + j * 16 + lr, ks * 32 + lk * 8);
            #pragma unroll
            for (int i = 0; i < 4; ++i)
                #pragma unroll
                for (int j = 0; j < 2; ++j)
                    acc[i][j] = __builtin_amdgcn_mfma_f32_16x16x32_bf16(
                        af[i], bfr[j], acc[i][j], 0, 0, 0);
        }
    }

    #pragma unroll
    for (int j = 0; j < 2; ++j) {
        int col = wn + j * 16 + lr;
        float bv = b1[h * C1 + col];
        #pragma unroll
        for (int i = 0; i < 4; ++i) {
            int t0 = wm + i * 16 + lk * 4;
            union { ushort q[4]; uint2 v; } pk;
            #pragma unroll
            for (int r = 0; r < 4; ++r) pk.q[r] = f2bf(acc[i][j][r] + bv);
            *(uint2*)&WHT_(col, t0) = pk.v;
        }
    }
    __syncthreads();

    // ---- scores (ss/ddv into Pb pad; stag is dead now) ----
    {
        int t = tid & 127;
        bool isS = tid < 128;
        const float* av = (isS ? a1s : a1d) + h * C1;
        float s = isS ? a1b[h] : 0.f;
        #pragma unroll 8
        for (int c = 0; c < 64; ++c) s = fmaf(bf2f(WHT_(c, t)), av[c], s);
        if (isS) SS_(t) = s; else DDV_(t) = s;
    }
    __syncthreads();

    // ---- P~ + row sums ----
    {
        float dm = fmaxf(DDV_(lane), DDV_(lane + 64));
        #pragma unroll
        for (int msk = 1; msk < 64; msk <<= 1) dm = fmaxf(dm, __shfl_xor(dm, msk));
        int i = tid >> 1, j0 = (tid & 1) * 64;
        float si = SS_(i);
        float mx = si + dm; mx = mx >= 0.f ? mx : ALPHA * mx;
        float lsum = 0.f;
        #pragma unroll
        for (int g = 0; g < 8; ++g) {
            union { ushort q[8]; uint4 v; } pk;
            #pragma unroll
            for (int e = 0; e < 8; ++e) {
                float ee = si + DDV_(j0 + g * 8 + e);
                ee = ee >= 0.f ? ee : ALPHA * ee;
                float pp = __expf(ee - mx);
                lsum += pp;
                pk.q[e] = f2bf(pp);
            }
            *(uint4*)&PB_(i, j0 + g * 8) = pk.v;
        }
        lsum += __shfl_xor(lsum, 1);
        if (!(tid & 1)) sinv[i] = 1.0f / lsum;
    }
    __syncthreads();

    // ---- PV MFMA ----
    f32x4 acc2[4][2];
    #pragma unroll
    for (int i = 0; i < 4; ++i)
        #pragma unroll
        for (int j = 0; j < 2; ++j) acc2[i][j] = (f32x4){0.f, 0.f, 0.f, 0.f};

    #pragma unroll
    for (int ks = 0; ks < 4; ++ks) {
        short8 af[4], bfr[2];
        #pragma unroll
        for (int i = 0; i < 4; ++i)
            af[i] = *(const short8*)&PB_(wm + i * 16 + lr, ks * 32 + lk * 8);
        #pragma unroll
        for (int j = 0; j < 2; ++j)
            bfr[j] = *(const short8*)&WHT_(wn + j * 16 + lr, ks * 32 + lk * 8);
        #pragma unroll
        for (int i = 0; i < 4; ++i)
            #pragma unroll
            for (int j = 0; j < 2; ++j)
                acc2[i][j] = __builtin_amdgcn_mfma_f32_16x16x32_bf16(
                    af[i], bfr[j], acc2[i][j], 0, 0, 0);
    }

    // ---- coalesced epilogue: restage in LDS (reuse Pb), then uint4 rows ----
    __syncthreads();                       // all PV ds_reads complete
    ushort* CT = u.Pb;                     // [128][72] (stride 72 => 16B align)
    #pragma unroll
    for (int i = 0; i < 4; ++i) {
        #pragma unroll
        for (int r = 0; r < 4; ++r) {
            int row = wm + i * 16 + lk * 4 + r;
            float sv = sinv[row];
            #pragma unroll
            for (int j = 0; j < 2; ++j) {
                int col = wn + j * 16 + lr;
                float v = acc2[i][j][r] * sv;
                v = v > 0.f ? v : 0.f;
                v = 1.0f / (1.0f + __expf(-v));
                CT[row * 72 + col] = f2bf(v);
            }
        }
    }
    __syncthreads();
    // 128 rows x 64 ushorts = 1024 chunks of 8 ushorts each.
    #pragma unroll
    for (int e = 0; e < 4; ++e) {
        int idx = e * 256 + tid;           // 0..1023: row = idx>>3, q = idx&7
        int row = idx >> 3, q = idx & 7;
        uint4 v = *(const uint4*)&CT[row * 72 + q * 8];
        *(uint4*)&c1[((size_t)(b * T + row)) * K2 + h * C1 + q * 8] = v;
    }
}

// ---------------------------------------------------------------------------
// FUSED kernel 2: split-K reduce (+bias) from PERMUTED partials -> scores ->
// P~ -> PV MFMA -> coalesced c2 write via LDS restage. whT2 stride 136
// (REQUIRED: t-index goes to 128).
// ---------------------------------------------------------------------------
#define PB2_(r,c)  Pb2[(r) * 136 + (c)]
#define WHT2_(r,c) whT2[(r) * 136 + (c)]

__global__ __launch_bounds__(256) void fused2_kernel(
    const ushort* __restrict__ wh2pb,  // [8] x permuted [2048][1280] bf16
    const float* __restrict__ b2,      // [1280] ([h][c] flat)
    const float* __restrict__ a2s, const float* __restrict__ a2d,
    const float* __restrict__ a2b,
    ushort* __restrict__ c2)
{
    int blk = blockIdx.x; int b = blk >> 6, h = blk & 63;
    __shared__ ushort Pb2[128 * 136];
    __shared__ ushort whT2[32 * 136];
    __shared__ float ss[128], ddv[128], sinv[128];

    int tid = threadIdx.x;
    int wave = tid >> 6, lane = tid & 63;
    int lr = lane & 15, lk = lane >> 4;
    const size_t MNfull = (size_t)2048 * F2;

    // ---- load + split-K reduce (permuted layout) + transpose ----
    for (int e = 0; e < 10; ++e) {
        int idx = e * 256 + tid;               // 0..2559
        int t = idx / 20, c = idx - t * 20;
        int col = h * C2 + c;
        int tn = col >> 7, cl = col & 127;
        int wv = ((t >> 6) << 1) | (cl >> 6);
        int fi = (t >> 4) & 3, fk = (t >> 2) & 3, fr = t & 3;
        int fj = (cl >> 4) & 3, fl = cl & 15;
        size_t fa = (size_t)(b * 10 + tn) * 16384 + wv * 4096
                  + (fi * 4 + fj) * 256 + (fk * 16 + fl) * 4 + fr;
        float s = b2[col];
        #pragma unroll
        for (int p = 0; p < 8; ++p) s += bf2f(wh2pb[p * MNfull + fa]);
        WHT2_(c, t) = f2bf(s);
    }
    {   // zero-pad rows 20..31
        int idx = tid;
        for (int e = 0; e < 6; ++e, idx += 256) {
            int c = 20 + (idx >> 7), t = idx & 127;
            WHT2_(c, t) = 0;
        }
    }
    __syncthreads();

    // ---- scores ----
    {
        int t = tid & 127;
        bool isS = tid < 128;
        const float* av = (isS ? a2s : a2d) + h * C2;
        float s = isS ? a2b[h] : 0.f;
        #pragma unroll
        for (int c = 0; c < 20; ++c) s = fmaf(bf2f(WHT2_(c, t)), av[c], s);
        if (isS) ss[t] = s; else ddv[t] = s;
    }
    __syncthreads();

    // ---- P~ + row sums ----
    {
        float dm = fmaxf(ddv[lane], ddv[lane + 64]);
        #pragma unroll
        for (int msk = 1; msk < 64; msk <<= 1) dm = fmaxf(dm, __shfl_xor(dm, msk));
        int i = tid >> 1, j0 = (tid & 1) * 64;
        float si = ss[i];
        float mx = si + dm; mx = mx >= 0.f ? mx : ALPHA * mx;
        float lsum = 0.f;
        #pragma unroll
        for (int g = 0; g < 8; ++g) {
            union { ushort q[8]; uint4 v; } pk;
            #pragma unroll
            for (int e = 0; e < 8; ++e) {
                float ee = si + ddv[j0 + g * 8 + e];
                ee = ee >= 0.f ? ee : ALPHA * ee;
                float pp = __expf(ee - mx);
                lsum += pp;
                pk.q[e] = f2bf(pp);
            }
            *(uint4*)&PB2_(i, j0 + g * 8) = pk.v;
        }
        lsum += __shfl_xor(lsum, 1);
        if (!(tid & 1)) sinv[i] = 1.0f / lsum;
    }
    __syncthreads();

    // ---- PV: out[128][32] = P~ @ whT2^T; wave owns 32 rows ----
    int wm2 = wave * 32;
    f32x4 acc2[2][2];
    #pragma unroll
    for (int i = 0; i < 2; ++i)
        #pragma unroll
        for (int j = 0; j < 2; ++j) acc2[i][j] = (f32x4){0.f, 0.f, 0.f, 0.f};

    #pragma unroll
    for (int ks = 0; ks < 4; ++ks) {
        short8 af[2], bfr[2];
        #pragma unroll
        for (int i = 0; i < 2; ++i)
            af[i] = *(const short8*)&PB2_(wm2 + i * 16 + lr, ks * 32 + lk * 8);
        #pragma unroll
        for (int j = 0; j < 2; ++j)
            bfr[j] = *(const short8*)&WHT2_(j * 16 + lr, ks * 32 + lk * 8);
        #pragma unroll
        for (int i = 0; i < 2; ++i)
            #pragma unroll
            for (int j = 0; j < 2; ++j)
                acc2[i][j] = __builtin_amdgcn_mfma_f32_16x16x32_bf16(
                    af[i], bfr[j], acc2[i][j], 0, 0, 0);
    }

    // ---- coalesced epilogue via LDS restage (reuse Pb2) ----
    __syncthreads();
    ushort* CT2 = Pb2;                     // [128][24]
    #pragma unroll
    for (int i = 0; i < 2; ++i) {
        #pragma unroll
        for (int r = 0; r < 4; ++r) {
            int row = wm2 + i * 16 + lk * 4 + r;
            float sv = sinv[row];
            #pragma unroll
            for (int j = 0; j < 2; ++j) {
                int col = j * 16 + lr;
                if (col < C2) {
                    float v = acc2[i][j][r] * sv;
                    v = v > 0.f ? v : 0.f;
                    v = 1.0f / (1.0f + __expf(-v));
                    CT2[row * 24 + col] = f2bf(v);
                }
            }
        }
    }
    __syncthreads();
    for (int e = 0; e < 3; ++e) {
        int idx = e * 256 + tid;           // 0..639: row = idx/5, q = idx%5
        if (idx < 640) {
            int row = idx / 5, q = idx - row * 5;
            uint2 v = *(const uint2*)&CT2[row * 24 + q * 4];
            *(uint2*)&c2[((size_t)(b * T + row)) * F2 + h * C2 + q * 4] = v;
        }
    }
}

// ---------------------------------------------------------------------------
// Prep kernels
// ---------------------------------------------------------------------------
__global__ __launch_bounds__(256) void xbf_kernel(
    const float* __restrict__ x, ushort* __restrict__ xbf)
{
    int i = blockIdx.x * 256 + threadIdx.x;
    float4 v = *(const float4*)&x[(size_t)i * 4];
    union { ushort u[4]; uint2 p; } o;
    o.u[0] = f2bf(v.x); o.u[1] = f2bf(v.y);
    o.u[2] = f2bf(v.z); o.u[3] = f2bf(v.w);
    *(uint2*)&xbf[(size_t)i * 4] = o.p;
}

__global__ __launch_bounds__(256) void w1t_kernel(
    const float* __restrict__ W1, ushort* __restrict__ w1t)
{
    int blk = blockIdx.x; int h = blk >> 2, d0 = (blk & 3) * 64;
    __shared__ float lw[64][65];
    int tid = threadIdx.x;
    for (int e = 0; e < 16; ++e) {
        int idx = e * 256 + tid; int dr = idx >> 6, c = idx & 63;
        lw[dr][c] = W1[((size_t)h * D + d0 + dr) * C1 + c];
    }
    __syncthreads();
    for (int e = 0; e < 16; ++e) {
        int idx = e * 256 + tid; int c = idx >> 6, dr = idx & 63;
        w1t[((size_t)(h * 64 + c)) * D + d0 + dr] = f2bf(lw[dr][c]);
    }
}

__global__ __launch_bounds__(256) void w2t_kernel(
    const float* __restrict__ W2, ushort* __restrict__ w2t)
{
    int blk = blockIdx.x; int h = blk >> 5, kb = blk & 31; int k0 = kb * 128;
    __shared__ float lw[128][21];
    int tid = threadIdx.x;
    const float* src = W2 + ((size_t)h * K2 + k0) * C2;
    for (int e = 0; e < 10; ++e) {
        int idx = e * 256 + tid; int k = idx / 20, c = idx - k * 20;
        lw[k][c] = src[idx];
    }
    __syncthreads();
    for (int e = 0; e < 10; ++e) {
        int idx = e * 256 + tid; int c = idx >> 7, k = idx & 127;
        w2t[((size_t)(h * 20 + c)) * K2 + k0 + k] = f2bf(lw[k][c]);
    }
}

__global__ __launch_bounds__(256) void slwt_kernel(
    const float* __restrict__ slw, ushort* __restrict__ slwt)
{
    int blk = blockIdx.x; int kb = blk >> 2, d0 = (blk & 3) * 64; int k0 = kb * 64;
    __shared__ float lw[64][65];
    int tid = threadIdx.x;
    for (int e = 0; e < 16; ++e) {
        int idx = e * 256 + tid; int kr = idx >> 6, dc = idx & 63;
        lw[kr][dc] = slw[((size_t)(k0 + kr)) * D + d0 + dc];
    }
    __syncthreads();
    for (int e = 0; e < 16; ++e) {
        int idx = e * 256 + tid; int dr = idx >> 6, kc = idx & 63;
        slwt[((size_t)(d0 + dr)) * F2 + k0 + kc] = f2bf(lw[kc][dr]);
    }
}

// ---------------------------------------------------------------------------
// GAR: res[b,o,d] = sum_t c3[b,t,d]*gar_w[t,o] + gar_b[o]
// ---------------------------------------------------------------------------
__global__ __launch_bounds__(256) void gar_kernel(
    const float* __restrict__ c3, const float* __restrict__ garw,
    const float* __restrict__ garb, float* __restrict__ out)
{
    int blk = blockIdx.x; int b = blk >> 5, o = blk & 31;
    int dcol = threadIdx.x;
    float acc = garb[o];
    const float* cp = c3 + (size_t)b * T * D + dcol;
    for (int t = 0; t < T; ++t)
        acc = fmaf(cp[(size_t)t * D], garw[t * OUTW + o], acc);
    out[((size_t)b * OUTW + o) * D + dcol] = acc;
}

// ---------------------------------------------------------------------------
extern "C" void kernel_launch(void* const* d_in, const int* in_sizes, int n_in,
                              void* d_out, int out_size, void* d_ws, size_t ws_size,
                              hipStream_t stream) {
    const float* x    = (const float*)d_in[0];
    const float* W1   = (const float*)d_in[1];
    const float* b1   = (const float*)d_in[2];
    const float* a1s  = (const float*)d_in[3];
    const float* a1d  = (const float*)d_in[4];
    const float* a1b  = (const float*)d_in[5];
    const float* W2   = (const float*)d_in[6];
    const float* b2   = (const float*)d_in[7];
    const float* a2s  = (const float*)d_in[8];
    const float* a2d  = (const float*)d_in[9];
    const float* a2b  = (const float*)d_in[10];
    const float* slw  = (const float*)d_in[11];
    const float* slb  = (const float*)d_in[12];
    const float* garw = (const float*)d_in[13];
    const float* garb = (const float*)d_in[14];

    char* p = (char*)d_ws;
    float*  c3    = (float*)p;   p += (size_t)2048 * 256  * 4;     //  2.1 MB
    ushort* xbf   = (ushort*)p;  p += (size_t)2048 * 256  * 2;     //  1.0 MB
    ushort* w1t   = (ushort*)p;  p += (size_t)4096 * 256  * 2;     //  2.1 MB
    ushort* c1bf  = (ushort*)p;  p += (size_t)2048 * 4096 * 2;     // 16.8 MB
    ushort* w2t   = (ushort*)p;  p += (size_t)1280 * 4096 * 2;     // 10.5 MB
    ushort* c2bf  = (ushort*)p;  p += (size_t)2048 * 1280 * 2;     //  5.2 MB
    ushort* slwt  = (ushort*)p;  p += (size_t)256  * 1280 * 2;     //  0.7 MB
    ushort* wh2pb = (ushort*)p;  p += (size_t)8 * 2048 * 1280 * 2; // 42 MB
    ushort* c3pb  = (ushort*)c1bf;   // aliases c1bf (dead after gemm2 reads it)

    xbf_kernel <<<512,  256, 0, stream>>>(x, xbf);
    w1t_kernel <<<256,  256, 0, stream>>>(W1, w1t);
    w2t_kernel <<<2048, 256, 0, stream>>>(W2, w2t);
    slwt_kernel<<<80,   256, 0, stream>>>(slw, slwt);

    fused1_kernel<<<B * H, 256, 0, stream>>>(xbf, w1t, b1, a1s, a1d, a1b, c1bf);

    gemm_splitk_kernel<4096, 10, 16, 8, 1><<<1280, 256, 0, stream>>>(c1bf, w2t,
                                                                     wh2pb);
    fused2_kernel<<<B * H, 256, 0, stream>>>(wh2pb, b2, a2s, a2d, a2b, c2bf);

    gemm_splitk_kernel<1280, 2, 16, 4, 0><<<128, 256, 0, stream>>>(c2bf, slwt,
                                                                   c3pb);
    reduce_bias_kernel<4, 256><<<512, 256, 0, stream>>>(c3pb, slb, c3, 2048 * 256);

    gar_kernel<<<B * OUTW, 256, 0, stream>>>(c3, garw, garb, (float*)d_out);
}